// Round 9
// baseline (294.836 us; speedup 1.0000x reference)
//
#include <hip/hip_runtime.h>
#include <hip/hip_cooperative_groups.h>

namespace cg = cooperative_groups;

// CustomMultiheadAttention on MI355X (gfx950).
// B=4 T=1024 S=1024 H=16 D=64 E=1024. Output fp32 [B,T,E].
//
// r9: ONE cooperative kernel (512 blocks x 256 threads), 3 phases separated by
// grid.sync() -- removes the ~22us of inter-kernel launch/drain overhead
// measured via the r6 replication experiment.
//   Phase 1: proj Q/K/V + Wout cvt (r8 task body, loop over 6656 tasks).
//   Phase 2: attn -- byte-identical to r8's verified kernel.
//   Phase 3: out_proj -- 128x64 tile, 4 waves as 2m x 2n (64x32/wave).
//
// Workspace (22 MB):
//   [0,8MB) qs bf16 [B*H,T,D] | [8,10) kb [H,S,D] | [10,12) vt [H,D,S]
//   [12,20) ctx bf16 [B*T,E]  | [20,22) wb [E,E]

typedef __attribute__((ext_vector_type(8))) short short8v;
typedef __attribute__((ext_vector_type(4))) short short4v;
typedef __attribute__((ext_vector_type(4))) float float4v;

#define MFMA_BF16(A, B, C) __builtin_amdgcn_mfma_f32_16x16x32_bf16(A, B, C, 0, 0, 0)

#if __has_builtin(__builtin_amdgcn_exp2f)
#define EXP2F(x) __builtin_amdgcn_exp2f(x)
#else
#define EXP2F(x) exp2f(x)
#endif

#define QSCALE 0.045084220027780106f   // log2(e)/32

__device__ __forceinline__ short f2bf(float f) {
  union { float f; unsigned u; } v; v.f = f;
  unsigned r = v.u + 0x7FFFu + ((v.u >> 16) & 1u);
  return (short)(r >> 16);
}

__global__ __launch_bounds__(256, 2) void mha_fused(
    const float* __restrict__ query, const float* __restrict__ para,
    const float* __restrict__ Wq, const float* __restrict__ bq,
    const float* __restrict__ Wk, const float* __restrict__ bk,
    const float* __restrict__ Wv, const float* __restrict__ bv,
    const float* __restrict__ Wout, const float* __restrict__ bout,
    short* __restrict__ qs, short* __restrict__ kb, short* __restrict__ vt,
    short* __restrict__ ctx, short* __restrict__ wb,
    float* __restrict__ out) {
  // LDS arena: phase 2 uses 26624B (kv 16384 + plds 10240);
  //            phase 3 uses 24576B (A 8KB + B 4KB, double-buffered).
  __shared__ __align__(16) char smem[26624];

  cg::grid_group grid = cg::this_grid();
  const int tid = threadIdx.x;
  const int w = tid >> 6;
  const int lane = tid & 63;
  const int g = lane >> 4, c = lane & 15;

  // ========================== Phase 1: proj + cvt ==========================
  for (int task = blockIdx.x * 4 + w; task < 6656; task += 2048) {
    if (task >= 6144) {   // cvt Wout -> wb (512 wave-tasks, 2048 elems each)
      const int j = task - 6144;
      const float* src = Wout + j * 2048;
      short* dst = wb + j * 2048;
#pragma unroll
      for (int it = 0; it < 4; ++it) {
        const int off = it * 512 + lane * 8;
        float4v x0 = *(const float4v*)(src + off);
        float4v x1 = *(const float4v*)(src + off + 4);
        short8v v = (short8v){ f2bf(x0.x), f2bf(x0.y), f2bf(x0.z), f2bf(x0.w),
                               f2bf(x1.x), f2bf(x1.y), f2bf(x1.z), f2bf(x1.w) };
        *(short8v*)(dst + off) = v;
      }
      continue;
    }

    const float* W;
    const float* bias;
    const float* xrow;
    int type, h, tile, bh = 0;
    if (task < 4096) {
      type = 0; bh = task >> 6; tile = task & 63; h = bh & 15;
      xrow = query + ((bh >> 4) * 1024 + tile * 16 + c) * 1024 + h * 64;
      W = Wq; bias = bq;
    } else if (task < 5120) {
      int idx = task - 4096;
      type = 1; h = idx >> 6; tile = idx & 63;
      xrow = para + (tile * 16 + c) * 1024 + h * 64;
      W = Wk; bias = bk;
    } else {
      int idx = task - 5120;
      type = 2; h = idx >> 6; tile = idx & 63;
      xrow = para + (tile * 16 + c) * 1024 + h * 64;
      W = Wv; bias = bv;
    }

    short8v af[2];
#pragma unroll
    for (int kh = 0; kh < 2; ++kh) {
      const float* xp = xrow + kh * 32 + g * 8;
      float4v x0 = *(const float4v*)xp;
      float4v x1 = *(const float4v*)(xp + 4);
      af[kh] = (short8v){ f2bf(x0.x), f2bf(x0.y), f2bf(x0.z), f2bf(x0.w),
                          f2bf(x1.x), f2bf(x1.y), f2bf(x1.z), f2bf(x1.w) };
    }

#pragma unroll
    for (int dn = 0; dn < 4; ++dn) {
      float4v acc = (float4v){0.f, 0.f, 0.f, 0.f};
#pragma unroll
      for (int kh = 0; kh < 2; ++kh) {
        const float* wp = W + (dn * 16 + c) * 64 + kh * 32 + g * 8;
        float4v w0 = *(const float4v*)wp;
        float4v w1 = *(const float4v*)(wp + 4);
        short8v bfr = (short8v){ f2bf(w0.x), f2bf(w0.y), f2bf(w0.z), f2bf(w0.w),
                                 f2bf(w1.x), f2bf(w1.y), f2bf(w1.z), f2bf(w1.w) };
        acc = MFMA_BF16(af[kh], bfr, acc);
      }
      const float bc = bias[dn * 16 + c];
      if (type == 0) {
#pragma unroll
        for (int r = 0; r < 4; ++r) {
          const int t = tile * 16 + 4 * g + r;
          qs[(bh * 1024 + t) * 64 + dn * 16 + c] = f2bf((acc[r] + bc) * QSCALE);
        }
      } else if (type == 1) {
#pragma unroll
        for (int r = 0; r < 4; ++r) {
          const int s = tile * 16 + 4 * g + r;
          kb[(h * 1024 + s) * 64 + dn * 16 + c] = f2bf(acc[r] + bc);
        }
      } else {
        short4v pk = (short4v){ f2bf(acc[0] + bc), f2bf(acc[1] + bc),
                                f2bf(acc[2] + bc), f2bf(acc[3] + bc) };
        *(short4v*)(vt + (h * 64 + dn * 16 + c) * 1024 + tile * 16 + 4 * g) = pk;
      }
    }
  }

  __threadfence();
  grid.sync();

  // ========================== Phase 2: attention ==========================
  // r8-verified structure: 512 blocks x 4 waves, 32 t-rows/wave; K/V tiles
  // reg-staged shared LDS dbuf; swapped QK^T; ones-MFMA denominator.
  {
    short* kvs = (short*)smem;                   // [2][4096] shorts
    short* plds = (short*)(smem + 16384);        // [4][2][16][40] shorts
    const int bh = blockIdx.x & 63;              // XCD-swizzle
    const int b = bh >> 4, h = bh & 15;
    const int t0 = (blockIdx.x >> 6) * 128 + w * 32;

    const int kr = tid >> 3, kq = (tid & 7) ^ (kr & 7);
    const char* ksrc = (const char*)(kb + h * 65536) + kr * 128 + kq * 16;
    const int vd = tid >> 2, vq = (tid & 3) ^ ((vd >> 1) & 3);
    const char* vsrc = (const char*)(vt + h * 65536) + vd * 2048 + vq * 16;
    char* kdst = (char*)kvs + tid * 16;
    char* vdst = (char*)kvs + 4096 + tid * 16;

    int koff[2][2];
#pragma unroll
    for (int sm = 0; sm < 2; ++sm)
#pragma unroll
      for (int kh = 0; kh < 2; ++kh)
        koff[sm][kh] = (sm * 16 + c) * 128 + (((kh * 4 + g) ^ (c & 7)) * 16);
    int voff[4];
#pragma unroll
    for (int nt = 0; nt < 4; ++nt)
      voff[nt] = 4096 + (nt * 16 + c) * 64 + ((g ^ ((c >> 1) & 3)) * 16);

    const short* qbase = qs + (bh * 1024 + t0) * 64;
    short8v qf[2][2];
#pragma unroll
    for (int tn = 0; tn < 2; ++tn)
#pragma unroll
      for (int kh = 0; kh < 2; ++kh)
        qf[tn][kh] = *(const short8v*)(qbase + (tn * 16 + c) * 64 + kh * 32 + g * 8);

    float4v cacc[2][4];
#pragma unroll
    for (int tn = 0; tn < 2; ++tn)
#pragma unroll
      for (int nt = 0; nt < 4; ++nt)
        cacc[tn][nt] = (float4v){0.f, 0.f, 0.f, 0.f};
    float4v dacc[2];
    dacc[0] = (float4v){0.f, 0.f, 0.f, 0.f};
    dacc[1] = (float4v){0.f, 0.f, 0.f, 0.f};
    const short obf = (short)0x3F80;   // bf16 1.0
    const short8v ones = (short8v){obf, obf, obf, obf, obf, obf, obf, obf};

    short8v sk = *(const short8v*)ksrc;
    short8v sv = *(const short8v*)vsrc;
    *(short8v*)kdst = sk;
    *(short8v*)vdst = sv;

    const char* kv0 = (const char*)kvs;
    for (int i = 0; i < 32; ++i) {
      __syncthreads();
      if (i < 31) {
        sk = *(const short8v*)(ksrc + (i + 1) * 4096);
        sv = *(const short8v*)(vsrc + (i + 1) * 64);
      }

      const char* kvb = kv0 + (i & 1) * 8192;
      short8v kf[2][2];
#pragma unroll
      for (int sm = 0; sm < 2; ++sm)
#pragma unroll
        for (int kh = 0; kh < 2; ++kh)
          kf[sm][kh] = *(const short8v*)(kvb + koff[sm][kh]);
      short8v vf[4];
#pragma unroll
      for (int nt = 0; nt < 4; ++nt)
        vf[nt] = *(const short8v*)(kvb + voff[nt]);

#pragma unroll
      for (int sm = 0; sm < 2; ++sm)
#pragma unroll
        for (int tn = 0; tn < 2; ++tn) {
          float4v z = (float4v){0.f, 0.f, 0.f, 0.f};
          z = MFMA_BF16(kf[sm][0], qf[tn][0], z);
          z = MFMA_BF16(kf[sm][1], qf[tn][1], z);
          const float p0 = EXP2F(z[0]);
          const float p1 = EXP2F(z[1]);
          const float p2 = EXP2F(z[2]);
          const float p3 = EXP2F(z[3]);
          short4v pk = (short4v){ f2bf(p0), f2bf(p1), f2bf(p2), f2bf(p3) };
          *(short4v*)&plds[(((w * 2) + tn) * 16 + c) * 40 + sm * 16 + 4 * g] = pk;
        }

      asm volatile("" ::: "memory");

      short8v pa[2];
#pragma unroll
      for (int tn = 0; tn < 2; ++tn)
        pa[tn] = *(const short8v*)&plds[(((w * 2) + tn) * 16 + c) * 40 + g * 8];

#pragma unroll
      for (int tn = 0; tn < 2; ++tn) {
#pragma unroll
        for (int nt = 0; nt < 4; ++nt)
          cacc[tn][nt] = MFMA_BF16(pa[tn], vf[nt], cacc[tn][nt]);
        dacc[tn] = MFMA_BF16(pa[tn], ones, dacc[tn]);
      }

      asm volatile("" ::: "memory");

      if (i < 31) {
        *(short8v*)(kdst + ((i + 1) & 1) * 8192) = sk;
        *(short8v*)(vdst + ((i + 1) & 1) * 8192) = sv;
      }
    }

    const int orow0 = b * 1024 + t0;
#pragma unroll
    for (int tn = 0; tn < 2; ++tn) {
      float inv[4];
#pragma unroll
      for (int r = 0; r < 4; ++r) inv[r] = 1.0f / dacc[tn][r];
#pragma unroll
      for (int nt = 0; nt < 4; ++nt)
#pragma unroll
        for (int r = 0; r < 4; ++r) {
          const int row = orow0 + tn * 16 + 4 * g + r;
          ctx[row * 1024 + h * 64 + nt * 16 + c] = f2bf(cacc[tn][nt][r] * inv[r]);
        }
    }
  }

  __threadfence();
  grid.sync();

  // ========================== Phase 3: out_proj ==========================
  // 512 blocks, 1 tile (128m x 64n) each; 4 waves as 2m x 2n (64x32/wave).
  // A+B LDS-staged dbuf, r8's verified swizzle: [r][ch] = X[r][ch^((r>>1)&3)].
  {
    short* ab = (short*)smem;                    // [2][6144] shorts
    const int wm = w >> 1, wn = w & 1;
    const int mblk = (blockIdx.x & 31) * 128;
    const int n0 = (blockIdx.x >> 5) * 64;

    // staging (256 threads): A rows srow & srow+64 (same chunk XOR: 64>>1 % 4 == 0),
    // B rows srow; linear LDS dest = tid*16 within each 4KB region.
    const int srow = tid >> 2;                   // 0..63
    const int sq = (tid & 3) ^ ((srow >> 1) & 3);
    const char* asrc0 = (const char*)ctx + (mblk + srow) * 2048 + sq * 16;
    const char* asrc1 = asrc0 + 64 * 2048;
    const char* bsrc  = (const char*)wb + (n0 + srow) * 2048 + sq * 16;
    char* adst0 = (char*)ab + tid * 16;
    char* adst1 = (char*)ab + 4096 + tid * 16;
    char* bdst  = (char*)ab + 8192 + tid * 16;

    const int sw = (g ^ ((c >> 1) & 3)) * 16;
    int aoff[4], boff[2];
#pragma unroll
    for (int mt = 0; mt < 4; ++mt)
      aoff[mt] = (wm * 64 + mt * 16 + c) * 64 + sw;
#pragma unroll
    for (int nt = 0; nt < 2; ++nt)
      boff[nt] = 8192 + (wn * 32 + nt * 16 + c) * 64 + sw;

    float4v acc[4][2];
#pragma unroll
    for (int mt = 0; mt < 4; ++mt)
#pragma unroll
      for (int nt = 0; nt < 2; ++nt)
        acc[mt][nt] = (float4v){0.f, 0.f, 0.f, 0.f};

    // prologue: k-tile 0 -> buf 0  (LDS safely reusable: grid.sync passed)
    short8v sa0 = *(const short8v*)asrc0;
    short8v sa1 = *(const short8v*)asrc1;
    short8v sbv = *(const short8v*)bsrc;
    *(short8v*)adst0 = sa0;
    *(short8v*)adst1 = sa1;
    *(short8v*)bdst = sbv;

    const char* ab0 = (const char*)ab;
    for (int i = 0; i < 32; ++i) {
      __syncthreads();
      if (i < 31) {
        sa0 = *(const short8v*)(asrc0 + (i + 1) * 64);
        sa1 = *(const short8v*)(asrc1 + (i + 1) * 64);
        sbv = *(const short8v*)(bsrc + (i + 1) * 64);
      }
      const char* abb = ab0 + (i & 1) * 12288;
      short8v a[4], bb[2];
#pragma unroll
      for (int mt = 0; mt < 4; ++mt)
        a[mt] = *(const short8v*)(abb + aoff[mt]);
#pragma unroll
      for (int nt = 0; nt < 2; ++nt)
        bb[nt] = *(const short8v*)(abb + boff[nt]);
#pragma unroll
      for (int mt = 0; mt < 4; ++mt)
#pragma unroll
        for (int nt = 0; nt < 2; ++nt)
          acc[mt][nt] = MFMA_BF16(a[mt], bb[nt], acc[mt][nt]);
      if (i < 31) {
        *(short8v*)(adst0 + ((i + 1) & 1) * 12288) = sa0;
        *(short8v*)(adst1 + ((i + 1) & 1) * 12288) = sa1;
        *(short8v*)(bdst + ((i + 1) & 1) * 12288) = sbv;
      }
    }

    float bs[2];
#pragma unroll
    for (int nt = 0; nt < 2; ++nt) bs[nt] = bout[n0 + wn * 32 + nt * 16 + c];

    const int m0 = mblk + wm * 64;
#pragma unroll
    for (int mt = 0; mt < 4; ++mt)
#pragma unroll
      for (int nt = 0; nt < 2; ++nt)
#pragma unroll
        for (int r = 0; r < 4; ++r)
          out[(m0 + mt * 16 + 4 * g + r) * 1024 + n0 + wn * 32 + nt * 16 + c] =
              acc[mt][nt][r] + bs[nt];
  }
}

// ---------------------------------------------------------------------------
extern "C" void kernel_launch(void* const* d_in, const int* in_sizes, int n_in,
                              void* d_out, int out_size, void* d_ws, size_t ws_size,
                              hipStream_t stream) {
  const float* query = (const float*)d_in[0];
  const float* para  = (const float*)d_in[1];
  const float* Wq = (const float*)d_in[2];
  const float* bq = (const float*)d_in[3];
  const float* Wk = (const float*)d_in[4];
  const float* bk = (const float*)d_in[5];
  const float* Wv = (const float*)d_in[6];
  const float* bv = (const float*)d_in[7];
  const float* Wout = (const float*)d_in[8];
  const float* bout = (const float*)d_in[9];
  float* out = (float*)d_out;

  char* ws = (char*)d_ws;
  short* qs  = (short*)(ws);                      // 8 MB
  short* kb  = (short*)(ws + (8u  << 20));        // 2 MB
  short* vt  = (short*)(ws + (10u << 20));        // 2 MB
  short* ctx = (short*)(ws + (12u << 20));        // 8 MB
  short* wb  = (short*)(ws + (20u << 20));        // 2 MB

  void* args[] = { &query, &para, &Wq, &bq, &Wk, &bk, &Wv, &bv, &Wout, &bout,
                   &qs, &kb, &vt, &ctx, &wb, &out };
  hipLaunchCooperativeKernel((const void*)mha_fused, dim3(512), dim3(256),
                             args, 0, stream);
}

// Round 10
// 79.313 us; speedup vs baseline: 3.7174x; 3.7174x over previous
//
#include <hip/hip_runtime.h>

// CustomMultiheadAttention on MI355X (gfx950).
// B=4 T=1024 S=1024 H=16 D=64 E=1024. Output fp32 [B,T,E].
//
// r10: back to 3 kernels (r9's cooperative fusion: grid.sync() ~115us each ->
// 280us kernel; reverted). Both LDS-bound kernels re-tiled for LDS-per-MFMA:
//   proj_qkv : r8 verbatim (passed r7/r8/r9).
//   attn_fwd : 256 blocks x 4 waves, 64 t-rows/wave (tn=0..3) -- K/V/staging
//              LDS ops amortized over 2x MFMAs; 1 block/CU, tail-free.
//              Same verified congruences/arithmetic as r8 (bitwise output).
//   out_proj : r9's phase-3 (validated in r9's passing run) standalone:
//              512 blocks x 4 waves as 2m x 2n (64x32/wave), A+B LDS dbuf.
//
// Workspace (22 MB):
//   [0,8MB) qs bf16 [B*H,T,D] | [8,10) kb [H,S,D] | [10,12) vt [H,D,S]
//   [12,20) ctx bf16 [B*T,E]  | [20,22) wb [E,E]

typedef __attribute__((ext_vector_type(8))) short short8v;
typedef __attribute__((ext_vector_type(4))) short short4v;
typedef __attribute__((ext_vector_type(4))) float float4v;

#define MFMA_BF16(A, B, C) __builtin_amdgcn_mfma_f32_16x16x32_bf16(A, B, C, 0, 0, 0)

#if __has_builtin(__builtin_amdgcn_exp2f)
#define EXP2F(x) __builtin_amdgcn_exp2f(x)
#else
#define EXP2F(x) exp2f(x)
#endif

#define QSCALE 0.045084220027780106f   // log2(e)/32

__device__ __forceinline__ short f2bf(float f) {
  union { float f; unsigned u; } v; v.f = f;
  unsigned r = v.u + 0x7FFFu + ((v.u >> 16) & 1u);
  return (short)(r >> 16);
}

// ---------------------------------------------------------------------------
// Kernel 1: per-head Q/K/V projections via MFMA + Wout fp32->bf16 cvt
// (tasks 6144..6655). Identical to r7/r8 (passed).
// ---------------------------------------------------------------------------
__global__ __launch_bounds__(256) void proj_qkv(
    const float* __restrict__ query, const float* __restrict__ para,
    const float* __restrict__ Wq, const float* __restrict__ bq,
    const float* __restrict__ Wk, const float* __restrict__ bk,
    const float* __restrict__ Wv, const float* __restrict__ bv,
    const float* __restrict__ Wout,
    short* __restrict__ qs, short* __restrict__ kb, short* __restrict__ vt,
    short* __restrict__ wb) {
  const int task = blockIdx.x * 4 + (threadIdx.x >> 6);
  const int lane = threadIdx.x & 63;
  const int g = lane >> 4, c = lane & 15;

  if (task >= 6144) {   // ---- cvt Wout -> wb (512 wave-tasks, 2048 elems each)
    const int j = task - 6144;
    const float* src = Wout + j * 2048;
    short* dst = wb + j * 2048;
#pragma unroll
    for (int it = 0; it < 4; ++it) {
      const int off = it * 512 + lane * 8;
      float4v x0 = *(const float4v*)(src + off);
      float4v x1 = *(const float4v*)(src + off + 4);
      short8v v = (short8v){ f2bf(x0.x), f2bf(x0.y), f2bf(x0.z), f2bf(x0.w),
                             f2bf(x1.x), f2bf(x1.y), f2bf(x1.z), f2bf(x1.w) };
      *(short8v*)(dst + off) = v;
    }
    return;
  }

  const float* W;
  const float* bias;
  const float* xrow;
  int type, h, tile, bh = 0;
  if (task < 4096) {
    type = 0; bh = task >> 6; tile = task & 63; h = bh & 15;
    xrow = query + ((bh >> 4) * 1024 + tile * 16 + c) * 1024 + h * 64;
    W = Wq; bias = bq;
  } else if (task < 5120) {
    int idx = task - 4096;
    type = 1; h = idx >> 6; tile = idx & 63;
    xrow = para + (tile * 16 + c) * 1024 + h * 64;
    W = Wk; bias = bk;
  } else {
    int idx = task - 5120;
    type = 2; h = idx >> 6; tile = idx & 63;
    xrow = para + (tile * 16 + c) * 1024 + h * 64;
    W = Wv; bias = bv;
  }

  short8v af[2];
#pragma unroll
  for (int kh = 0; kh < 2; ++kh) {
    const float* xp = xrow + kh * 32 + g * 8;
    float4v x0 = *(const float4v*)xp;
    float4v x1 = *(const float4v*)(xp + 4);
    af[kh] = (short8v){ f2bf(x0.x), f2bf(x0.y), f2bf(x0.z), f2bf(x0.w),
                        f2bf(x1.x), f2bf(x1.y), f2bf(x1.z), f2bf(x1.w) };
  }

#pragma unroll
  for (int dn = 0; dn < 4; ++dn) {
    float4v acc = (float4v){0.f, 0.f, 0.f, 0.f};
#pragma unroll
    for (int kh = 0; kh < 2; ++kh) {
      const float* wp = W + (dn * 16 + c) * 64 + kh * 32 + g * 8;
      float4v w0 = *(const float4v*)wp;
      float4v w1 = *(const float4v*)(wp + 4);
      short8v bfr = (short8v){ f2bf(w0.x), f2bf(w0.y), f2bf(w0.z), f2bf(w0.w),
                               f2bf(w1.x), f2bf(w1.y), f2bf(w1.z), f2bf(w1.w) };
      acc = MFMA_BF16(af[kh], bfr, acc);
    }
    const float bc = bias[dn * 16 + c];
    if (type == 0) {
#pragma unroll
      for (int r = 0; r < 4; ++r) {
        const int t = tile * 16 + 4 * g + r;
        qs[(bh * 1024 + t) * 64 + dn * 16 + c] = f2bf((acc[r] + bc) * QSCALE);
      }
    } else if (type == 1) {
#pragma unroll
      for (int r = 0; r < 4; ++r) {
        const int s = tile * 16 + 4 * g + r;
        kb[(h * 1024 + s) * 64 + dn * 16 + c] = f2bf(acc[r] + bc);
      }
    } else {
      short4v pk = (short4v){ f2bf(acc[0] + bc), f2bf(acc[1] + bc),
                              f2bf(acc[2] + bc), f2bf(acc[3] + bc) };
      *(short4v*)(vt + (h * 64 + dn * 16 + c) * 1024 + tile * 16 + 4 * g) = pk;
    }
  }
}

// ---------------------------------------------------------------------------
// Kernel 2: attention. 256 blocks (bh x ttile256) x 4 waves, 64 t-rows/wave
// (tn=0..3). 1 block/CU, tail-free. K/V tiles reg-staged shared LDS dbuf
// (r8-verified congruences); swapped QK^T; ones-MFMA denominator.
//   LDS_K[r][ch] = K[r][ch ^ (r&7)]        (32 rows x 8 x 16B chunks)
//   LDS_V[d][ch] = V[d][ch ^ ((d>>1)&3)]   (64 rows x 4 x 16B chunks)
// ---------------------------------------------------------------------------
__global__ __launch_bounds__(256, 1) void attn_fwd(
    const short* __restrict__ qs, const short* __restrict__ kb,
    const short* __restrict__ vt, short* __restrict__ ctx) {
  __shared__ __align__(16) short kv[2][4096];         // per buf: K 4KB | V 4KB
  __shared__ __align__(16) short plds[4][4][16][40];  // per-wave P tiles (tn=0..3)
  const int tid = threadIdx.x;
  const int w = tid >> 6;
  const int lane = tid & 63;
  const int g = lane >> 4, c = lane & 15;
  const int bh = blockIdx.x & 63;          // XCD-swizzle: bh%8 == XCD
  const int b = bh >> 4, h = bh & 15;
  const int t0 = (blockIdx.x >> 6) * 256 + w * 64;

  const int kr = tid >> 3, kq = (tid & 7) ^ (kr & 7);
  const char* ksrc = (const char*)(kb + h * 65536) + kr * 128 + kq * 16;
  const int vd = tid >> 2, vq = (tid & 3) ^ ((vd >> 1) & 3);
  const char* vsrc = (const char*)(vt + h * 65536) + vd * 2048 + vq * 16;
  char* kdst = (char*)&kv[0][0] + tid * 16;
  char* vdst = (char*)&kv[0][0] + 4096 + tid * 16;

  int koff[2][2];
#pragma unroll
  for (int sm = 0; sm < 2; ++sm)
#pragma unroll
    for (int kh = 0; kh < 2; ++kh)
      koff[sm][kh] = (sm * 16 + c) * 128 + (((kh * 4 + g) ^ (c & 7)) * 16);
  int voff[4];
#pragma unroll
  for (int nt = 0; nt < 4; ++nt)
    voff[nt] = 4096 + (nt * 16 + c) * 64 + ((g ^ ((c >> 1) & 3)) * 16);

  const short* qbase = qs + (bh * 1024 + t0) * 64;
  short8v qf[4][2];
#pragma unroll
  for (int tn = 0; tn < 4; ++tn)
#pragma unroll
    for (int kh = 0; kh < 2; ++kh)
      qf[tn][kh] = *(const short8v*)(qbase + (tn * 16 + c) * 64 + kh * 32 + g * 8);

  float4v cacc[4][4];
#pragma unroll
  for (int tn = 0; tn < 4; ++tn)
#pragma unroll
    for (int nt = 0; nt < 4; ++nt)
      cacc[tn][nt] = (float4v){0.f, 0.f, 0.f, 0.f};
  float4v dacc[4];
#pragma unroll
  for (int tn = 0; tn < 4; ++tn) dacc[tn] = (float4v){0.f, 0.f, 0.f, 0.f};
  const short obf = (short)0x3F80;   // bf16 1.0
  const short8v ones = (short8v){obf, obf, obf, obf, obf, obf, obf, obf};

  short8v sk = *(const short8v*)ksrc;
  short8v sv = *(const short8v*)vsrc;
  *(short8v*)kdst = sk;
  *(short8v*)vdst = sv;

  const char* kv0 = (const char*)&kv[0][0];
  for (int i = 0; i < 32; ++i) {
    __syncthreads();            // buf(i&1) ready; other buf free for writes
    if (i < 31) {               // issue next-tile loads early
      sk = *(const short8v*)(ksrc + (i + 1) * 4096);
      sv = *(const short8v*)(vsrc + (i + 1) * 64);
    }

    const char* kvb = kv0 + (i & 1) * 8192;
    short8v kf[2][2];
#pragma unroll
    for (int sm = 0; sm < 2; ++sm)
#pragma unroll
      for (int kh = 0; kh < 2; ++kh)
        kf[sm][kh] = *(const short8v*)(kvb + koff[sm][kh]);
    short8v vf[4];
#pragma unroll
    for (int nt = 0; nt < 4; ++nt)
      vf[nt] = *(const short8v*)(kvb + voff[nt]);

    // scores^T -> exp2 -> scalar pack into plds
#pragma unroll
    for (int sm = 0; sm < 2; ++sm)
#pragma unroll
      for (int tn = 0; tn < 4; ++tn) {
        float4v z = (float4v){0.f, 0.f, 0.f, 0.f};
        z = MFMA_BF16(kf[sm][0], qf[tn][0], z);
        z = MFMA_BF16(kf[sm][1], qf[tn][1], z);
        const float p0 = EXP2F(z[0]);
        const float p1 = EXP2F(z[1]);
        const float p2 = EXP2F(z[2]);
        const float p3 = EXP2F(z[3]);
        short4v pk = (short4v){ f2bf(p0), f2bf(p1), f2bf(p2), f2bf(p3) };
        *(short4v*)&plds[w][tn][c][sm * 16 + 4 * g] = pk;
      }

    asm volatile("" ::: "memory");   // order P write -> P read (same wave)

    short8v pa[4];
#pragma unroll
    for (int tn = 0; tn < 4; ++tn)
      pa[tn] = *(const short8v*)&plds[w][tn][c][g * 8];  // m=c(t), k=8g+j(s)

#pragma unroll
    for (int tn = 0; tn < 4; ++tn) {
#pragma unroll
      for (int nt = 0; nt < 4; ++nt)
        cacc[tn][nt] = MFMA_BF16(pa[tn], vf[nt], cacc[tn][nt]);
      dacc[tn] = MFMA_BF16(pa[tn], ones, dacc[tn]);   // rowsum(P), matrix pipe
    }

    asm volatile("" ::: "memory");

    if (i < 31) {   // write tile i+1 into the other buffer
      *(short8v*)(kdst + ((i + 1) & 1) * 8192) = sk;
      *(short8v*)(vdst + ((i + 1) & 1) * 8192) = sv;
    }
  }

  const int orow0 = b * 1024 + t0;
#pragma unroll
  for (int tn = 0; tn < 4; ++tn) {
    float inv[4];
#pragma unroll
    for (int r = 0; r < 4; ++r) inv[r] = 1.0f / dacc[tn][r];
#pragma unroll
    for (int nt = 0; nt < 4; ++nt)
#pragma unroll
      for (int r = 0; r < 4; ++r) {
        const int row = orow0 + tn * 16 + 4 * g + r;
        ctx[row * 1024 + h * 64 + nt * 16 + c] = f2bf(cacc[tn][nt][r] * inv[r]);
      }
  }
}

// ---------------------------------------------------------------------------
// Kernel 3: out = ctx(bf16) @ Wout^T + bout. r9-phase-3 (validated) standalone:
// 512 blocks (32m x 16n, 128x64 tile) x 4 waves as 2m x 2n (64x32/wave).
// A+B LDS-staged dbuf; LDS content [r][ch] = X[r][ch ^ ((r>>1)&3)].
// ---------------------------------------------------------------------------
__global__ __launch_bounds__(256, 2) void out_proj(
    const short* __restrict__ ctx, const short* __restrict__ wb,
    const float* __restrict__ bout, float* __restrict__ out) {
  __shared__ __align__(16) short ab[2][6144];   // per buf: A 8KB | B 4KB
  const int tid = threadIdx.x;
  const int w = tid >> 6;
  const int lane = tid & 63;
  const int g = lane >> 4, c = lane & 15;
  const int wm = w >> 1, wn = w & 1;
  const int mblk = (blockIdx.x & 31) * 128;
  const int n0 = (blockIdx.x >> 5) * 64;

  // staging (256 threads): A rows srow & srow+64 (same chunk XOR), B rows srow.
  const int srow = tid >> 2;                   // 0..63
  const int sq = (tid & 3) ^ ((srow >> 1) & 3);
  const char* asrc0 = (const char*)ctx + (mblk + srow) * 2048 + sq * 16;
  const char* asrc1 = asrc0 + 64 * 2048;
  const char* bsrc  = (const char*)wb + (n0 + srow) * 2048 + sq * 16;
  char* adst0 = (char*)&ab[0][0] + tid * 16;
  char* adst1 = (char*)&ab[0][0] + 4096 + tid * 16;
  char* bdst  = (char*)&ab[0][0] + 8192 + tid * 16;

  const int sw = (g ^ ((c >> 1) & 3)) * 16;
  int aoff[4], boff[2];
#pragma unroll
  for (int mt = 0; mt < 4; ++mt)
    aoff[mt] = (wm * 64 + mt * 16 + c) * 64 + sw;
#pragma unroll
  for (int nt = 0; nt < 2; ++nt)
    boff[nt] = 8192 + (wn * 32 + nt * 16 + c) * 64 + sw;

  float4v acc[4][2];
#pragma unroll
  for (int mt = 0; mt < 4; ++mt)
#pragma unroll
    for (int nt = 0; nt < 2; ++nt)
      acc[mt][nt] = (float4v){0.f, 0.f, 0.f, 0.f};

  // prologue: k-tile 0 -> buf 0
  short8v sa0 = *(const short8v*)asrc0;
  short8v sa1 = *(const short8v*)asrc1;
  short8v sbv = *(const short8v*)bsrc;
  *(short8v*)adst0 = sa0;
  *(short8v*)adst1 = sa1;
  *(short8v*)bdst = sbv;

  const char* ab0 = (const char*)&ab[0][0];
  for (int i = 0; i < 32; ++i) {
    __syncthreads();
    if (i < 31) {
      sa0 = *(const short8v*)(asrc0 + (i + 1) * 64);
      sa1 = *(const short8v*)(asrc1 + (i + 1) * 64);
      sbv = *(const short8v*)(bsrc + (i + 1) * 64);
    }
    const char* abb = ab0 + (i & 1) * 12288;
    short8v a[4], bb[2];
#pragma unroll
    for (int mt = 0; mt < 4; ++mt)
      a[mt] = *(const short8v*)(abb + aoff[mt]);
#pragma unroll
    for (int nt = 0; nt < 2; ++nt)
      bb[nt] = *(const short8v*)(abb + boff[nt]);
#pragma unroll
    for (int mt = 0; mt < 4; ++mt)
#pragma unroll
      for (int nt = 0; nt < 2; ++nt)
        acc[mt][nt] = MFMA_BF16(a[mt], bb[nt], acc[mt][nt]);
    if (i < 31) {
      *(short8v*)(adst0 + ((i + 1) & 1) * 12288) = sa0;
      *(short8v*)(adst1 + ((i + 1) & 1) * 12288) = sa1;
      *(short8v*)(bdst + ((i + 1) & 1) * 12288) = sbv;
    }
  }

  float bs[2];
#pragma unroll
  for (int nt = 0; nt < 2; ++nt) bs[nt] = bout[n0 + wn * 32 + nt * 16 + c];

  const int m0 = mblk + wm * 64;
#pragma unroll
  for (int mt = 0; mt < 4; ++mt)
#pragma unroll
    for (int nt = 0; nt < 2; ++nt)
#pragma unroll
      for (int r = 0; r < 4; ++r)
        out[(m0 + mt * 16 + 4 * g + r) * 1024 + n0 + wn * 32 + nt * 16 + c] =
            acc[mt][nt][r] + bs[nt];
}

// ---------------------------------------------------------------------------
extern "C" void kernel_launch(void* const* d_in, const int* in_sizes, int n_in,
                              void* d_out, int out_size, void* d_ws, size_t ws_size,
                              hipStream_t stream) {
  const float* query = (const float*)d_in[0];
  const float* para  = (const float*)d_in[1];
  const float* Wq = (const float*)d_in[2];
  const float* bq = (const float*)d_in[3];
  const float* Wk = (const float*)d_in[4];
  const float* bk = (const float*)d_in[5];
  const float* Wv = (const float*)d_in[6];
  const float* bv = (const float*)d_in[7];
  const float* Wout = (const float*)d_in[8];
  const float* bout = (const float*)d_in[9];
  float* out = (float*)d_out;

  char* ws = (char*)d_ws;
  short* qs  = (short*)(ws);                      // 8 MB
  short* kb  = (short*)(ws + (8u  << 20));        // 2 MB
  short* vt  = (short*)(ws + (10u << 20));        // 2 MB
  short* ctx = (short*)(ws + (12u << 20));        // 8 MB
  short* wb  = (short*)(ws + (20u << 20));        // 2 MB

  proj_qkv<<<dim3(1664), dim3(256), 0, stream>>>(query, para, Wq, bq, Wk, bk,
                                                 Wv, bv, Wout, qs, kb, vt, wb);
  attn_fwd<<<dim3(256), dim3(256), 0, stream>>>(qs, kb, vt, ctx);
  out_proj<<<dim3(512), dim3(256), 0, stream>>>(ctx, wb, bout, out);
}

// Round 11
// 65.146 us; speedup vs baseline: 4.5258x; 1.2175x over previous
//
#include <hip/hip_runtime.h>

// CustomMultiheadAttention on MI355X (gfx950).
// B=4 T=1024 S=1024 H=16 D=64 E=1024. Output fp32 [B,T,E].
//
// r11: attn back to r8 shape (512 blk x 4 waves x 32 rows, 2 blk/CU -- r10's
// 1 blk/CU was latency-serialized: 42.6us, VALUBusy 38%). Single new variable:
// softmax pack via v_cvt_pk_bf16_f32 (2 instr vs ~14 scalar VALU ops; r4's
// failure is now attributed to its bundled unroll-2, absent here -- this round
// is the controlled test). out_proj: r10's (measured ~8us). proj: r8's.
//
// Workspace (22 MB):
//   [0,8MB) qs bf16 [B*H,T,D] | [8,10) kb [H,S,D] | [10,12) vt [H,D,S]
//   [12,20) ctx bf16 [B*T,E]  | [20,22) wb [E,E]

typedef __attribute__((ext_vector_type(8))) short short8v;
typedef __attribute__((ext_vector_type(4))) short short4v;
typedef __attribute__((ext_vector_type(4))) float float4v;

#define MFMA_BF16(A, B, C) __builtin_amdgcn_mfma_f32_16x16x32_bf16(A, B, C, 0, 0, 0)

#if __has_builtin(__builtin_amdgcn_exp2f)
#define EXP2F(x) __builtin_amdgcn_exp2f(x)
#else
#define EXP2F(x) exp2f(x)
#endif

#define QSCALE 0.045084220027780106f   // log2(e)/32

__device__ __forceinline__ short f2bf(float f) {
  union { float f; unsigned u; } v; v.f = f;
  unsigned r = v.u + 0x7FFFu + ((v.u >> 16) & 1u);
  return (short)(r >> 16);
}

// pack 2 f32 -> 2 bf16 (RNE); S0 -> low half (standard AMD pk semantics)
__device__ __forceinline__ unsigned cvt_pk_bf16(float lo, float hi) {
  unsigned r;
  asm("v_cvt_pk_bf16_f32 %0, %1, %2" : "=v"(r) : "v"(lo), "v"(hi));
  return r;
}

// ---------------------------------------------------------------------------
// Kernel 1: per-head Q/K/V projections via MFMA + Wout fp32->bf16 cvt
// (tasks 6144..6655). Identical to r7/r8/r10 (passed).
// ---------------------------------------------------------------------------
__global__ __launch_bounds__(256) void proj_qkv(
    const float* __restrict__ query, const float* __restrict__ para,
    const float* __restrict__ Wq, const float* __restrict__ bq,
    const float* __restrict__ Wk, const float* __restrict__ bk,
    const float* __restrict__ Wv, const float* __restrict__ bv,
    const float* __restrict__ Wout,
    short* __restrict__ qs, short* __restrict__ kb, short* __restrict__ vt,
    short* __restrict__ wb) {
  const int task = blockIdx.x * 4 + (threadIdx.x >> 6);
  const int lane = threadIdx.x & 63;
  const int g = lane >> 4, c = lane & 15;

  if (task >= 6144) {   // ---- cvt Wout -> wb (512 wave-tasks, 2048 elems each)
    const int j = task - 6144;
    const float* src = Wout + j * 2048;
    short* dst = wb + j * 2048;
#pragma unroll
    for (int it = 0; it < 4; ++it) {
      const int off = it * 512 + lane * 8;
      float4v x0 = *(const float4v*)(src + off);
      float4v x1 = *(const float4v*)(src + off + 4);
      short8v v = (short8v){ f2bf(x0.x), f2bf(x0.y), f2bf(x0.z), f2bf(x0.w),
                             f2bf(x1.x), f2bf(x1.y), f2bf(x1.z), f2bf(x1.w) };
      *(short8v*)(dst + off) = v;
    }
    return;
  }

  const float* W;
  const float* bias;
  const float* xrow;
  int type, h, tile, bh = 0;
  if (task < 4096) {
    type = 0; bh = task >> 6; tile = task & 63; h = bh & 15;
    xrow = query + ((bh >> 4) * 1024 + tile * 16 + c) * 1024 + h * 64;
    W = Wq; bias = bq;
  } else if (task < 5120) {
    int idx = task - 4096;
    type = 1; h = idx >> 6; tile = idx & 63;
    xrow = para + (tile * 16 + c) * 1024 + h * 64;
    W = Wk; bias = bk;
  } else {
    int idx = task - 5120;
    type = 2; h = idx >> 6; tile = idx & 63;
    xrow = para + (tile * 16 + c) * 1024 + h * 64;
    W = Wv; bias = bv;
  }

  short8v af[2];
#pragma unroll
  for (int kh = 0; kh < 2; ++kh) {
    const float* xp = xrow + kh * 32 + g * 8;
    float4v x0 = *(const float4v*)xp;
    float4v x1 = *(const float4v*)(xp + 4);
    af[kh] = (short8v){ f2bf(x0.x), f2bf(x0.y), f2bf(x0.z), f2bf(x0.w),
                        f2bf(x1.x), f2bf(x1.y), f2bf(x1.z), f2bf(x1.w) };
  }

#pragma unroll
  for (int dn = 0; dn < 4; ++dn) {
    float4v acc = (float4v){0.f, 0.f, 0.f, 0.f};
#pragma unroll
    for (int kh = 0; kh < 2; ++kh) {
      const float* wp = W + (dn * 16 + c) * 64 + kh * 32 + g * 8;
      float4v w0 = *(const float4v*)wp;
      float4v w1 = *(const float4v*)(wp + 4);
      short8v bfr = (short8v){ f2bf(w0.x), f2bf(w0.y), f2bf(w0.z), f2bf(w0.w),
                               f2bf(w1.x), f2bf(w1.y), f2bf(w1.z), f2bf(w1.w) };
      acc = MFMA_BF16(af[kh], bfr, acc);
    }
    const float bc = bias[dn * 16 + c];
    if (type == 0) {
#pragma unroll
      for (int r = 0; r < 4; ++r) {
        const int t = tile * 16 + 4 * g + r;
        qs[(bh * 1024 + t) * 64 + dn * 16 + c] = f2bf((acc[r] + bc) * QSCALE);
      }
    } else if (type == 1) {
#pragma unroll
      for (int r = 0; r < 4; ++r) {
        const int s = tile * 16 + 4 * g + r;
        kb[(h * 1024 + s) * 64 + dn * 16 + c] = f2bf(acc[r] + bc);
      }
    } else {
      short4v pk = (short4v){ f2bf(acc[0] + bc), f2bf(acc[1] + bc),
                              f2bf(acc[2] + bc), f2bf(acc[3] + bc) };
      *(short4v*)(vt + (h * 64 + dn * 16 + c) * 1024 + tile * 16 + 4 * g) = pk;
    }
  }
}

// ---------------------------------------------------------------------------
// Kernel 2: attention. r8-exact structure (512 blocks x 4 waves, 32 t-rows per
// wave, 2 blocks/CU); ONLY change: P pack via v_cvt_pk_bf16_f32 (no unroll-2).
// ---------------------------------------------------------------------------
__global__ __launch_bounds__(256, 4) void attn_fwd(
    const short* __restrict__ qs, const short* __restrict__ kb,
    const short* __restrict__ vt, short* __restrict__ ctx) {
  __shared__ __align__(16) short kv[2][4096];         // per buf: K 4KB | V 4KB
  __shared__ __align__(16) short plds[4][2][16][40];  // per-wave P tiles
  const int tid = threadIdx.x;
  const int w = tid >> 6;
  const int lane = tid & 63;
  const int g = lane >> 4, c = lane & 15;
  const int bh = blockIdx.x & 63;          // XCD-swizzle: bh%8 == XCD
  const int b = bh >> 4, h = bh & 15;
  const int t0 = (blockIdx.x >> 6) * 128 + w * 32;

  const int kr = tid >> 3, kq = (tid & 7) ^ (kr & 7);
  const char* ksrc = (const char*)(kb + h * 65536) + kr * 128 + kq * 16;
  const int vd = tid >> 2, vq = (tid & 3) ^ ((vd >> 1) & 3);
  const char* vsrc = (const char*)(vt + h * 65536) + vd * 2048 + vq * 16;
  char* kdst = (char*)&kv[0][0] + tid * 16;
  char* vdst = (char*)&kv[0][0] + 4096 + tid * 16;

  int koff[2][2];
#pragma unroll
  for (int sm = 0; sm < 2; ++sm)
#pragma unroll
    for (int kh = 0; kh < 2; ++kh)
      koff[sm][kh] = (sm * 16 + c) * 128 + (((kh * 4 + g) ^ (c & 7)) * 16);
  int voff[4];
#pragma unroll
  for (int nt = 0; nt < 4; ++nt)
    voff[nt] = 4096 + (nt * 16 + c) * 64 + ((g ^ ((c >> 1) & 3)) * 16);

  const short* qbase = qs + (bh * 1024 + t0) * 64;
  short8v qf[2][2];
#pragma unroll
  for (int tn = 0; tn < 2; ++tn)
#pragma unroll
    for (int kh = 0; kh < 2; ++kh)
      qf[tn][kh] = *(const short8v*)(qbase + (tn * 16 + c) * 64 + kh * 32 + g * 8);

  float4v cacc[2][4];
#pragma unroll
  for (int tn = 0; tn < 2; ++tn)
#pragma unroll
    for (int nt = 0; nt < 4; ++nt)
      cacc[tn][nt] = (float4v){0.f, 0.f, 0.f, 0.f};
  float4v dacc[2];
  dacc[0] = (float4v){0.f, 0.f, 0.f, 0.f};
  dacc[1] = (float4v){0.f, 0.f, 0.f, 0.f};
  const short obf = (short)0x3F80;   // bf16 1.0
  const short8v ones = (short8v){obf, obf, obf, obf, obf, obf, obf, obf};

  short8v sk = *(const short8v*)ksrc;
  short8v sv = *(const short8v*)vsrc;
  *(short8v*)kdst = sk;
  *(short8v*)vdst = sv;

  const char* kv0 = (const char*)&kv[0][0];
  for (int i = 0; i < 32; ++i) {
    __syncthreads();            // buf(i&1) ready; other buf free for writes
    if (i < 31) {               // issue next-tile loads early
      sk = *(const short8v*)(ksrc + (i + 1) * 4096);
      sv = *(const short8v*)(vsrc + (i + 1) * 64);
    }

    const char* kvb = kv0 + (i & 1) * 8192;
    short8v kf[2][2];
#pragma unroll
    for (int sm = 0; sm < 2; ++sm)
#pragma unroll
      for (int kh = 0; kh < 2; ++kh)
        kf[sm][kh] = *(const short8v*)(kvb + koff[sm][kh]);
    short8v vf[4];
#pragma unroll
    for (int nt = 0; nt < 4; ++nt)
      vf[nt] = *(const short8v*)(kvb + voff[nt]);

    // scores^T -> exp2 -> cvt_pk pack into plds
#pragma unroll
    for (int sm = 0; sm < 2; ++sm)
#pragma unroll
      for (int tn = 0; tn < 2; ++tn) {
        float4v z = (float4v){0.f, 0.f, 0.f, 0.f};
        z = MFMA_BF16(kf[sm][0], qf[tn][0], z);
        z = MFMA_BF16(kf[sm][1], qf[tn][1], z);
        const float p0 = EXP2F(z[0]);
        const float p1 = EXP2F(z[1]);
        const float p2 = EXP2F(z[2]);
        const float p3 = EXP2F(z[3]);
        uint2 u;
        u.x = cvt_pk_bf16(p0, p1);   // [p0 lo | p1 hi] -> s=4g, 4g+1
        u.y = cvt_pk_bf16(p2, p3);   // [p2 lo | p3 hi] -> s=4g+2, 4g+3
        *(uint2*)&plds[w][tn][c][sm * 16 + 4 * g] = u;
      }

    asm volatile("" ::: "memory");   // order P write -> P read (same wave)

    short8v pa[2];
#pragma unroll
    for (int tn = 0; tn < 2; ++tn)
      pa[tn] = *(const short8v*)&plds[w][tn][c][g * 8];  // m=c(t), k=8g+j(s)

#pragma unroll
    for (int tn = 0; tn < 2; ++tn) {
#pragma unroll
      for (int nt = 0; nt < 4; ++nt)
        cacc[tn][nt] = MFMA_BF16(pa[tn], vf[nt], cacc[tn][nt]);
      dacc[tn] = MFMA_BF16(pa[tn], ones, dacc[tn]);   // rowsum(P), matrix pipe
    }

    asm volatile("" ::: "memory");

    if (i < 31) {   // write tile i+1 into the other buffer
      *(short8v*)(kdst + ((i + 1) & 1) * 8192) = sk;
      *(short8v*)(vdst + ((i + 1) & 1) * 8192) = sv;
    }
  }

  const int orow0 = b * 1024 + t0;
#pragma unroll
  for (int tn = 0; tn < 2; ++tn) {
    float inv[4];
#pragma unroll
    for (int r = 0; r < 4; ++r) inv[r] = 1.0f / dacc[tn][r];
#pragma unroll
    for (int nt = 0; nt < 4; ++nt)
#pragma unroll
      for (int r = 0; r < 4; ++r) {
        const int row = orow0 + tn * 16 + 4 * g + r;
        ctx[row * 1024 + h * 64 + nt * 16 + c] = f2bf(cacc[tn][nt][r] * inv[r]);
      }
  }
}

// ---------------------------------------------------------------------------
// Kernel 3: out = ctx(bf16) @ Wout^T + bout. r10-exact (measured ~8us):
// 512 blocks (32m x 16n, 128x64 tile) x 4 waves as 2m x 2n (64x32/wave).
// A+B LDS-staged dbuf; LDS content [r][ch] = X[r][ch ^ ((r>>1)&3)].
// ---------------------------------------------------------------------------
__global__ __launch_bounds__(256, 2) void out_proj(
    const short* __restrict__ ctx, const short* __restrict__ wb,
    const float* __restrict__ bout, float* __restrict__ out) {
  __shared__ __align__(16) short ab[2][6144];   // per buf: A 8KB | B 4KB
  const int tid = threadIdx.x;
  const int w = tid >> 6;
  const int lane = tid & 63;
  const int g = lane >> 4, c = lane & 15;
  const int wm = w >> 1, wn = w & 1;
  const int mblk = (blockIdx.x & 31) * 128;
  const int n0 = (blockIdx.x >> 5) * 64;

  // staging (256 threads): A rows srow & srow+64 (same chunk XOR), B rows srow.
  const int srow = tid >> 2;                   // 0..63
  const int sq = (tid & 3) ^ ((srow >> 1) & 3);
  const char* asrc0 = (const char*)ctx + (mblk + srow) * 2048 + sq * 16;
  const char* asrc1 = asrc0 + 64 * 2048;
  const char* bsrc  = (const char*)wb + (n0 + srow) * 2048 + sq * 16;
  char* adst0 = (char*)&ab[0][0] + tid * 16;
  char* adst1 = (char*)&ab[0][0] + 4096 + tid * 16;
  char* bdst  = (char*)&ab[0][0] + 8192 + tid * 16;

  const int sw = (g ^ ((c >> 1) & 3)) * 16;
  int aoff[4], boff[2];
#pragma unroll
  for (int mt = 0; mt < 4; ++mt)
    aoff[mt] = (wm * 64 + mt * 16 + c) * 64 + sw;
#pragma unroll
  for (int nt = 0; nt < 2; ++nt)
    boff[nt] = 8192 + (wn * 32 + nt * 16 + c) * 64 + sw;

  float4v acc[4][2];
#pragma unroll
  for (int mt = 0; mt < 4; ++mt)
#pragma unroll
    for (int nt = 0; nt < 2; ++nt)
      acc[mt][nt] = (float4v){0.f, 0.f, 0.f, 0.f};

  // prologue: k-tile 0 -> buf 0
  short8v sa0 = *(const short8v*)asrc0;
  short8v sa1 = *(const short8v*)asrc1;
  short8v sbv = *(const short8v*)bsrc;
  *(short8v*)adst0 = sa0;
  *(short8v*)adst1 = sa1;
  *(short8v*)bdst = sbv;

  const char* ab0 = (const char*)&ab[0][0];
  for (int i = 0; i < 32; ++i) {
    __syncthreads();
    if (i < 31) {
      sa0 = *(const short8v*)(asrc0 + (i + 1) * 64);
      sa1 = *(const short8v*)(asrc1 + (i + 1) * 64);
      sbv = *(const short8v*)(bsrc + (i + 1) * 64);
    }
    const char* abb = ab0 + (i & 1) * 12288;
    short8v a[4], bb[2];
#pragma unroll
    for (int mt = 0; mt < 4; ++mt)
      a[mt] = *(const short8v*)(abb + aoff[mt]);
#pragma unroll
    for (int nt = 0; nt < 2; ++nt)
      bb[nt] = *(const short8v*)(abb + boff[nt]);
#pragma unroll
    for (int mt = 0; mt < 4; ++mt)
#pragma unroll
      for (int nt = 0; nt < 2; ++nt)
        acc[mt][nt] = MFMA_BF16(a[mt], bb[nt], acc[mt][nt]);
    if (i < 31) {
      *(short8v*)(adst0 + ((i + 1) & 1) * 12288) = sa0;
      *(short8v*)(adst1 + ((i + 1) & 1) * 12288) = sa1;
      *(short8v*)(bdst + ((i + 1) & 1) * 12288) = sbv;
    }
  }

  float bs[2];
#pragma unroll
  for (int nt = 0; nt < 2; ++nt) bs[nt] = bout[n0 + wn * 32 + nt * 16 + c];

  const int m0 = mblk + wm * 64;
#pragma unroll
  for (int mt = 0; mt < 4; ++mt)
#pragma unroll
    for (int nt = 0; nt < 2; ++nt)
#pragma unroll
      for (int r = 0; r < 4; ++r)
        out[(m0 + mt * 16 + 4 * g + r) * 1024 + n0 + wn * 32 + nt * 16 + c] =
            acc[mt][nt][r] + bs[nt];
}

// ---------------------------------------------------------------------------
extern "C" void kernel_launch(void* const* d_in, const int* in_sizes, int n_in,
                              void* d_out, int out_size, void* d_ws, size_t ws_size,
                              hipStream_t stream) {
  const float* query = (const float*)d_in[0];
  const float* para  = (const float*)d_in[1];
  const float* Wq = (const float*)d_in[2];
  const float* bq = (const float*)d_in[3];
  const float* Wk = (const float*)d_in[4];
  const float* bk = (const float*)d_in[5];
  const float* Wv = (const float*)d_in[6];
  const float* bv = (const float*)d_in[7];
  const float* Wout = (const float*)d_in[8];
  const float* bout = (const float*)d_in[9];
  float* out = (float*)d_out;

  char* ws = (char*)d_ws;
  short* qs  = (short*)(ws);                      // 8 MB
  short* kb  = (short*)(ws + (8u  << 20));        // 2 MB
  short* vt  = (short*)(ws + (10u << 20));        // 2 MB
  short* ctx = (short*)(ws + (12u << 20));        // 8 MB
  short* wb  = (short*)(ws + (20u << 20));        // 2 MB

  proj_qkv<<<dim3(1664), dim3(256), 0, stream>>>(query, para, Wq, bq, Wk, bk,
                                                 Wv, bv, Wout, qs, kb, vt, wb);
  attn_fwd<<<dim3(512), dim3(256), 0, stream>>>(qs, kb, vt, ctx);
  out_proj<<<dim3(512), dim3(256), 0, stream>>>(ctx, wb, bout, out);
}